// Round 2
// baseline (123.642 us; speedup 1.0000x reference)
//
#include <hip/hip_runtime.h>
#include <hip/hip_bf16.h>

#define NB   2
#define SKV  1024
#define NSQ  512
#define HIN  256
#define HA   128

// projections pre-scaled by 2*log2(e):  exp2(KSC*x) = e^{2x}
// tanh(x) = 1 - 2/(e^{2x}+1)
#define KSC   2.8853900817779268f
#define LOG2E 1.4426950408889634f

// ---------------- Kernel A: projections (pre-scaled by KSC) ----------------
// rows [0,2048): pk[r] = (kv[r] @ W_kv + b_kv)*KSC ; rows [2048,3072): pq
__global__ __launch_bounds__(128) void proj_kernel(
    const float* __restrict__ kv,
    const float* __restrict__ qy,
    const float* __restrict__ Wkv,
    const float* __restrict__ bkv,
    const float* __restrict__ Wq,
    const float* __restrict__ bq,
    float* __restrict__ pk,
    float* __restrict__ pq)
{
    __shared__ __align__(16) float rowf[8][HIN];
    const int t  = threadIdx.x;            // 0..127 = output channel a
    const int r0 = blockIdx.x * 8;         // 8 rows per block
    const bool is_q = (r0 >= NB * SKV);
    const float* __restrict__ src = is_q ? (qy + (size_t)(r0 - NB * SKV) * HIN)
                                         : (kv + (size_t)r0 * HIN);
    const float* __restrict__ W  = is_q ? Wq : Wkv;
    const float* __restrict__ bs = is_q ? bq : bkv;
    float* __restrict__ dst = is_q ? (pq + (size_t)(r0 - NB * SKV) * HA)
                                   : (pk + (size_t)r0 * HA);

    // stage 8 rows x 256 f32 = 512 float4, 4 per thread (coalesced)
    const float4* __restrict__ s4 = (const float4*)src;
    float4* r4 = (float4*)&rowf[0][0];
    #pragma unroll
    for (int i = 0; i < 4; ++i) r4[t + i * 128] = s4[t + i * 128];
    __syncthreads();

    float a[8];
    #pragma unroll
    for (int i = 0; i < 8; ++i) a[i] = 0.f;
    #pragma unroll 4
    for (int h = 0; h < HIN; ++h) {
        float w = W[h * HA + t];           // coalesced f32 load (L2-hot)
        #pragma unroll
        for (int i = 0; i < 8; ++i) a[i] = fmaf(rowf[i][h], w, a[i]);  // LDS broadcast
    }
    const float bb = bs[t];
    #pragma unroll
    for (int i = 0; i < 8; ++i) dst[i * HA + t] = (a[i] + bb) * KSC;
}

// ---------------- Kernel B: fused score/softmax/output ----------------
// one block = 4 consecutive (b,q) rows; 512 threads (8 waves); grid 256
__global__ __launch_bounds__(512) void attn_kernel(
    const float* __restrict__ pk,          // (2048,128) scaled
    const float* __restrict__ pq,          // (1024,128) scaled
    const float* __restrict__ wv,          // (128)
    const float* __restrict__ bv,          // (1)
    const float* __restrict__ kv,          // (2048,256) f32
    float* __restrict__ out)               // [262144 out0][1048576 weights]
{
    __shared__ __align__(16) float eq_s[4][HA];     // exp2(scaled pq)
    __shared__ __align__(16) float wv_s[HA];
    __shared__ __align__(16) float wt_s[SKV][4];    // softmax weights, 4 q per row
    __shared__ float red[2][4][8];
    __shared__ float w0red[8];
    __shared__ __align__(16) float part[8][4][HIN]; // phase-4 partials (32 KB)

    const int tid  = threadIdx.x;
    const int lane = tid & 63, wid = tid >> 6;
    const int bq0  = blockIdx.x * 4;       // 4 never straddles b boundary (512%4==0)
    const int b    = bq0 >> 9;

    // ---- phase 1: Eq, wv, W0 = sum(wv) ----
    {
        const int row = tid >> 7, a = tid & 127;    // 4 x 128
        eq_s[row][a] = __builtin_amdgcn_exp2f(pq[(size_t)(bq0 + row) * HA + a]);
    }
    float w0p = (tid < HA) ? wv[tid] : 0.f;
    if (tid < HA) wv_s[tid] = w0p;
    #pragma unroll
    for (int o = 32; o > 0; o >>= 1) w0p += __shfl_down(w0p, o);
    if (lane == 0) w0red[wid] = w0p;
    const float bvf = bv[0];
    __syncthreads();
    float W0 = 0.f;
    #pragma unroll
    for (int i = 0; i < 8; ++i) W0 += w0red[i];

    // ---- phase 2: scores.  score = W0 - 2*sum_a wv_a/(E*Eq+1) + bv ----
    float sc[4][2];
    #pragma unroll
    for (int si = 0; si < 2; ++si) {
        const int s = si * 512 + tid;
        const float4* __restrict__ prow = (const float4*)(pk + (size_t)(b * SKV + s) * HA);
        const float4* __restrict__ wv4  = (const float4*)wv_s;
        const float4* __restrict__ q40  = (const float4*)&eq_s[0][0];
        const float4* __restrict__ q41  = (const float4*)&eq_s[1][0];
        const float4* __restrict__ q42  = (const float4*)&eq_s[2][0];
        const float4* __restrict__ q43  = (const float4*)&eq_s[3][0];
        float a0 = 0.f, a1 = 0.f, a2 = 0.f, a3 = 0.f;
        #pragma unroll 4
        for (int a4 = 0; a4 < 32; ++a4) {
            const float4 p  = prow[a4];
            const float4 w4 = wv4[a4];
            float4 E;
            E.x = __builtin_amdgcn_exp2f(p.x);
            E.y = __builtin_amdgcn_exp2f(p.y);
            E.z = __builtin_amdgcn_exp2f(p.z);
            E.w = __builtin_amdgcn_exp2f(p.w);
            const float4 q0 = q40[a4];
            const float4 q1 = q41[a4];
            const float4 q2 = q42[a4];
            const float4 q3 = q43[a4];
            a0 = fmaf(w4.x, __builtin_amdgcn_rcpf(fmaf(E.x, q0.x, 1.f)), a0);
            a1 = fmaf(w4.x, __builtin_amdgcn_rcpf(fmaf(E.x, q1.x, 1.f)), a1);
            a2 = fmaf(w4.x, __builtin_amdgcn_rcpf(fmaf(E.x, q2.x, 1.f)), a2);
            a3 = fmaf(w4.x, __builtin_amdgcn_rcpf(fmaf(E.x, q3.x, 1.f)), a3);
            a0 = fmaf(w4.y, __builtin_amdgcn_rcpf(fmaf(E.y, q0.y, 1.f)), a0);
            a1 = fmaf(w4.y, __builtin_amdgcn_rcpf(fmaf(E.y, q1.y, 1.f)), a1);
            a2 = fmaf(w4.y, __builtin_amdgcn_rcpf(fmaf(E.y, q2.y, 1.f)), a2);
            a3 = fmaf(w4.y, __builtin_amdgcn_rcpf(fmaf(E.y, q3.y, 1.f)), a3);
            a0 = fmaf(w4.z, __builtin_amdgcn_rcpf(fmaf(E.z, q0.z, 1.f)), a0);
            a1 = fmaf(w4.z, __builtin_amdgcn_rcpf(fmaf(E.z, q1.z, 1.f)), a1);
            a2 = fmaf(w4.z, __builtin_amdgcn_rcpf(fmaf(E.z, q2.z, 1.f)), a2);
            a3 = fmaf(w4.z, __builtin_amdgcn_rcpf(fmaf(E.z, q3.z, 1.f)), a3);
            a0 = fmaf(w4.w, __builtin_amdgcn_rcpf(fmaf(E.w, q0.w, 1.f)), a0);
            a1 = fmaf(w4.w, __builtin_amdgcn_rcpf(fmaf(E.w, q1.w, 1.f)), a1);
            a2 = fmaf(w4.w, __builtin_amdgcn_rcpf(fmaf(E.w, q2.w, 1.f)), a2);
            a3 = fmaf(w4.w, __builtin_amdgcn_rcpf(fmaf(E.w, q3.w, 1.f)), a3);
        }
        sc[0][si] = fmaf(-2.f, a0, W0) + bvf;
        sc[1][si] = fmaf(-2.f, a1, W0) + bvf;
        sc[2][si] = fmaf(-2.f, a2, W0) + bvf;
        sc[3][si] = fmaf(-2.f, a3, W0) + bvf;
    }

    // ---- phase 3: softmax over s (block-wide, 8 waves) ----
    #pragma unroll
    for (int q = 0; q < 4; ++q) {
        float m = fmaxf(sc[q][0], sc[q][1]);
        #pragma unroll
        for (int o = 32; o > 0; o >>= 1) m = fmaxf(m, __shfl_down(m, o));
        if (lane == 0) red[0][q][wid] = m;
    }
    __syncthreads();
    float M[4];
    #pragma unroll
    for (int q = 0; q < 4; ++q) {
        float m = red[0][q][0];
        #pragma unroll
        for (int i = 1; i < 8; ++i) m = fmaxf(m, red[0][q][i]);
        M[q] = m;
    }
    float e[4][2];
    #pragma unroll
    for (int q = 0; q < 4; ++q) {
        e[q][0] = __builtin_amdgcn_exp2f((sc[q][0] - M[q]) * LOG2E);
        e[q][1] = __builtin_amdgcn_exp2f((sc[q][1] - M[q]) * LOG2E);
        float sum = e[q][0] + e[q][1];
        #pragma unroll
        for (int o = 32; o > 0; o >>= 1) sum += __shfl_down(sum, o);
        if (lane == 0) red[1][q][wid] = sum;
    }
    __syncthreads();
    float rw[4];
    #pragma unroll
    for (int q = 0; q < 4; ++q) {
        float d = red[1][q][0];
        #pragma unroll
        for (int i = 1; i < 8; ++i) d += red[1][q][i];
        rw[q] = 1.0f / d;
    }

    float* __restrict__ outw = out + (size_t)NB * NSQ * HIN;   // weights at 262144
    #pragma unroll
    for (int si = 0; si < 2; ++si) {
        const int s = si * 512 + tid;
        #pragma unroll
        for (int q = 0; q < 4; ++q) {
            const float w = e[q][si] * rw[q];
            wt_s[s][q] = w;
            outw[(size_t)(bq0 + q) * SKV + s] = w;             // coalesced per q
        }
    }
    __syncthreads();

    // ---- phase 4: out[q][h] = sum_s w[q][s]*kv[b][s][h] ----
    // wave wid handles s in [wid*128, wid*128+128); lane = float4 chunk of h
    {
        const int g = wid;
        float4 ac0 = {0,0,0,0}, ac1 = {0,0,0,0}, ac2 = {0,0,0,0}, ac3 = {0,0,0,0};
        const float4* __restrict__ kvb =
            (const float4*)(kv + (size_t)(b * SKV + g * 128) * HIN);
        #pragma unroll 4
        for (int i = 0; i < 128; ++i) {
            const int s = g * 128 + i;
            const float4 w4 = *((const float4*)&wt_s[s][0]);   // LDS broadcast b128
            const float4 v  = kvb[(size_t)i * 64 + lane];      // coalesced 1KB/wave
            ac0.x = fmaf(w4.x, v.x, ac0.x); ac0.y = fmaf(w4.x, v.y, ac0.y);
            ac0.z = fmaf(w4.x, v.z, ac0.z); ac0.w = fmaf(w4.x, v.w, ac0.w);
            ac1.x = fmaf(w4.y, v.x, ac1.x); ac1.y = fmaf(w4.y, v.y, ac1.y);
            ac1.z = fmaf(w4.y, v.z, ac1.z); ac1.w = fmaf(w4.y, v.w, ac1.w);
            ac2.x = fmaf(w4.z, v.x, ac2.x); ac2.y = fmaf(w4.z, v.y, ac2.y);
            ac2.z = fmaf(w4.z, v.z, ac2.z); ac2.w = fmaf(w4.z, v.w, ac2.w);
            ac3.x = fmaf(w4.w, v.x, ac3.x); ac3.y = fmaf(w4.w, v.y, ac3.y);
            ac3.z = fmaf(w4.w, v.z, ac3.z); ac3.w = fmaf(w4.w, v.w, ac3.w);
        }
        ((float4*)part[g][0])[lane] = ac0;
        ((float4*)part[g][1])[lane] = ac1;
        ((float4*)part[g][2])[lane] = ac2;
        ((float4*)part[g][3])[lane] = ac3;
    }
    __syncthreads();
    #pragma unroll
    for (int k = 0; k < 2; ++k) {
        const int id = tid + k * 512;
        const int q = id >> 8, h = id & 255;
        float v = 0.f;
        #pragma unroll
        for (int g2 = 0; g2 < 8; ++g2) v += part[g2][q][h];    // stride-1 banks
        out[(size_t)(bq0 + q) * HIN + h] = v;                  // coalesced
    }
}

extern "C" void kernel_launch(void* const* d_in, const int* in_sizes, int n_in,
                              void* d_out, int out_size, void* d_ws, size_t ws_size,
                              hipStream_t stream) {
    (void)in_sizes; (void)n_in; (void)out_size; (void)ws_size;
    const float* kv  = (const float*)d_in[0];
    const float* qy  = (const float*)d_in[1];
    const float* Wkv = (const float*)d_in[2];
    const float* bkv = (const float*)d_in[3];
    const float* Wq  = (const float*)d_in[4];
    const float* bq  = (const float*)d_in[5];
    const float* wv  = (const float*)d_in[6];
    const float* bv  = (const float*)d_in[7];

    float* pk = (float*)d_ws;                 // 2048*128 f32 = 1 MB
    float* pq = pk + (size_t)NB * SKV * HA;   // 1024*128 f32 = 0.5 MB
    float* out = (float*)d_out;

    hipLaunchKernelGGL(proj_kernel, dim3((NB * SKV + NB * NSQ) / 8), dim3(128), 0, stream,
                       kv, qy, Wkv, bkv, Wq, bq, pk, pq);
    hipLaunchKernelGGL(attn_kernel, dim3(NB * NSQ / 4), dim3(512), 0, stream,
                       pk, pq, wv, bv, kv, out);
}